// Round 3
// baseline (399.384 us; speedup 1.0000x reference)
//
#include <hip/hip_runtime.h>
#include <stdint.h>

#define D 128
#define E_EDGES 50000
#define S_NEG 16
#define N_A 100000
#define N_B 50000
#define ES (E_EDGES * S_NEG)

#define CHUNK 12500   // items per hist block; also words per hist slab
#define A_COLS 76     // A chunk-cols: A0:0-3, A1:4-7, A2:8-11, A3:12-75 (x2 halves = 152 slabs)
#define B_SLABS 68    // B slabs: B0:0-3, B1:4-67
#define GA 1344       // scan blocks for the A table
#define GB 704        // scan blocks for the B table  (GA+GB = 2048 -> full occupancy)

// ---------------------------------------------------------------------------
// ws layout (4-byte words):
//   u32 partA[152 * CHUNK]  byte-hist slabs, slab = (chunkcol*2 + half)
//   u32 partB[ 68 * CHUNK]
//   int4 cntAi[N_A]         per-row counts {pos0, nh0, nh1, nt0}
//   int2 cntBi[N_B]         per-row counts {pos1, nt1}
//   f32 psumA[GA * 512]     scan1 per-block partials [plane0..3][128]
//   f32 psumB[GB * 256]
//   f32 cvec[6 * D]
//   f32 PA[N_A * 5],  f32 PB[N_B]
// ---------------------------------------------------------------------------

__global__ void k_hist(const int* __restrict__ ei0, const int* __restrict__ ei1,
                       const int* __restrict__ nh0, const int* __restrict__ nh1,
                       const int* __restrict__ nt0, const int* __restrict__ nt1,
                       uint32_t* __restrict__ partA, uint32_t* __restrict__ partB) {
    __shared__ uint32_t h[CHUNK];
    const int tid = threadIdx.x;
    for (int w = tid; w < CHUNK; w += 256) h[w] = 0;
    __syncthreads();

    const int b = blockIdx.x;
    const int* src; long long base; int stride, lo; uint32_t* dst;
    if (b < 8) {                       // A0: pos0 tails = ei0[E..2E)
        const int c = b >> 1, hh = b & 1;
        src = ei0; base = E_EDGES + (long long)c * CHUNK; stride = 1;
        lo = hh * 50000; dst = partA + (size_t)(c * 2 + hh) * CHUNK;
    } else if (b < 16) {               // A1: nh0 column 0
        const int q = b - 8, c = q >> 1, hh = q & 1;
        src = nh0; base = (long long)c * CHUNK * S_NEG; stride = S_NEG;
        lo = hh * 50000; dst = partA + (size_t)((4 + c) * 2 + hh) * CHUNK;
    } else if (b < 24) {               // A2: nh1 column 0
        const int q = b - 16, c = q >> 1, hh = q & 1;
        src = nh1; base = (long long)c * CHUNK * S_NEG; stride = S_NEG;
        lo = hh * 50000; dst = partA + (size_t)((8 + c) * 2 + hh) * CHUNK;
    } else if (b < 152) {              // A3: nt0 flat (800k, 64 chunks x 2 halves)
        const int q = b - 24, c = q >> 1, hh = q & 1;
        src = nt0; base = (long long)c * CHUNK; stride = 1;
        lo = hh * 50000; dst = partA + (size_t)((12 + c) * 2 + hh) * CHUNK;
    } else if (b < 156) {              // B0: pos1 tails = ei1[E..2E)
        const int c = b - 152;
        src = ei1; base = E_EDGES + (long long)c * CHUNK; stride = 1;
        lo = 0; dst = partB + (size_t)c * CHUNK;
    } else {                           // B1: nt1 flat (800k, 64 chunks)
        const int c = b - 156;
        src = nt1; base = (long long)c * CHUNK; stride = 1;
        lo = 0; dst = partB + (size_t)(4 + c) * CHUNK;
    }

    for (int i = tid; i < CHUNK; i += 256) {
        const unsigned r = (unsigned)(src[base + (long long)i * stride] - lo);
        if (r < 50000u) atomicAdd(&h[r >> 2], 1u << ((r & 3u) * 8u));
    }
    __syncthreads();
    for (int w = tid; w < CHUNK; w += 256) dst[w] = h[w];
}

// thread-per-bin: sum the byte partials -> interleaved int counts.
__global__ void k_reduceC(const uint32_t* __restrict__ partA,
                          const uint32_t* __restrict__ partB,
                          int4* __restrict__ cntAi, int2* __restrict__ cntBi) {
    const int t = blockIdx.x * 256 + threadIdx.x;
    if (t < N_A) {
        const int n = t;
        const int hh = (n >= 50000);
        const int w = (n - hh * 50000) >> 2;
        const int sh = (n & 3) * 8;
        const uint32_t* p = partA + (size_t)hh * CHUNK + w;
        unsigned s0 = 0, s1 = 0, s2 = 0, s3 = 0;
#pragma unroll
        for (int c = 0; c < 4; ++c)   s0 += (p[(size_t)(c * 2) * CHUNK] >> sh) & 255u;
#pragma unroll
        for (int c = 4; c < 8; ++c)   s1 += (p[(size_t)(c * 2) * CHUNK] >> sh) & 255u;
#pragma unroll
        for (int c = 8; c < 12; ++c)  s2 += (p[(size_t)(c * 2) * CHUNK] >> sh) & 255u;
#pragma unroll 8
        for (int c = 12; c < 76; ++c) s3 += (p[(size_t)(c * 2) * CHUNK] >> sh) & 255u;
        cntAi[n] = make_int4((int)s0, (int)s1, (int)s2, (int)s3);
    } else if (t < N_A + N_B) {
        const int n = t - N_A;
        const int w = n >> 2;
        const int sh = (n & 3) * 8;
        const uint32_t* p = partB + w;
        unsigned s0 = 0, s1 = 0;
#pragma unroll
        for (int c = 0; c < 4; ++c)   s0 += (p[(size_t)c * CHUNK] >> sh) & 255u;
#pragma unroll 8
        for (int c = 4; c < 68; ++c)  s1 += (p[(size_t)c * CHUNK] >> sh) & 255u;
        cntBi[n] = make_int2((int)s0, (int)s1);
    }
}

// Weighted table scan: per-block partial s_j written dense. No branches, no
// global atomics; int4 broadcast count load + float4 row load per iteration.
__global__ void k_scan1(const float* __restrict__ embA, const float* __restrict__ embB,
                        const int4* __restrict__ cntAi, const int2* __restrict__ cntBi,
                        float* __restrict__ psumA, float* __restrict__ psumB) {
    __shared__ float sds[4 * D];
    const int tid = threadIdx.x;
    const int l = tid & 31;
    const int grp = tid >> 5;  // 0..7

    for (int j = tid; j < 4 * D; j += 256) sds[j] = 0.f;
    __syncthreads();

    if ((int)blockIdx.x < GA) {
        float a0=0,a1=0,a2=0,a3=0, b0=0,b1=0,b2=0,b3=0;
        float c0=0,c1=0,c2=0,c3=0, d0=0,d1=0,d2=0,d3=0;
        for (int n = blockIdx.x * 8 + grp; n < N_A; n += GA * 8) {
            const int4 w = cntAi[n];
            const float4 r = *reinterpret_cast<const float4*>(embA + (size_t)n * D + 4 * l);
            float f;
            f = (float)w.x; a0 += f*r.x; a1 += f*r.y; a2 += f*r.z; a3 += f*r.w;
            f = (float)w.y; b0 += f*r.x; b1 += f*r.y; b2 += f*r.z; b3 += f*r.w;
            f = (float)w.z; c0 += f*r.x; c1 += f*r.y; c2 += f*r.z; c3 += f*r.w;
            f = (float)w.w; d0 += f*r.x; d1 += f*r.y; d2 += f*r.z; d3 += f*r.w;
        }
        atomicAdd(&sds[0*D + 4*l+0], a0); atomicAdd(&sds[0*D + 4*l+1], a1);
        atomicAdd(&sds[0*D + 4*l+2], a2); atomicAdd(&sds[0*D + 4*l+3], a3);
        atomicAdd(&sds[1*D + 4*l+0], b0); atomicAdd(&sds[1*D + 4*l+1], b1);
        atomicAdd(&sds[1*D + 4*l+2], b2); atomicAdd(&sds[1*D + 4*l+3], b3);
        atomicAdd(&sds[2*D + 4*l+0], c0); atomicAdd(&sds[2*D + 4*l+1], c1);
        atomicAdd(&sds[2*D + 4*l+2], c2); atomicAdd(&sds[2*D + 4*l+3], c3);
        atomicAdd(&sds[3*D + 4*l+0], d0); atomicAdd(&sds[3*D + 4*l+1], d1);
        atomicAdd(&sds[3*D + 4*l+2], d2); atomicAdd(&sds[3*D + 4*l+3], d3);
        __syncthreads();
        for (int j = tid; j < 4 * D; j += 256)
            psumA[(size_t)blockIdx.x * 512 + j] = sds[j];
    } else {
        const int bi = blockIdx.x - GA;
        float a0=0,a1=0,a2=0,a3=0, b0=0,b1=0,b2=0,b3=0;
        for (int n = bi * 8 + grp; n < N_B; n += GB * 8) {
            const int2 w = cntBi[n];
            const float4 r = *reinterpret_cast<const float4*>(embB + (size_t)n * D + 4 * l);
            float f;
            f = (float)w.x; a0 += f*r.x; a1 += f*r.y; a2 += f*r.z; a3 += f*r.w;
            f = (float)w.y; b0 += f*r.x; b1 += f*r.y; b2 += f*r.z; b3 += f*r.w;
        }
        atomicAdd(&sds[0*D + 4*l+0], a0); atomicAdd(&sds[0*D + 4*l+1], a1);
        atomicAdd(&sds[0*D + 4*l+2], a2); atomicAdd(&sds[0*D + 4*l+3], a3);
        atomicAdd(&sds[1*D + 4*l+0], b0); atomicAdd(&sds[1*D + 4*l+1], b1);
        atomicAdd(&sds[1*D + 4*l+2], b2); atomicAdd(&sds[1*D + 4*l+3], b3);
        __syncthreads();
        for (int j = tid; j < 2 * D; j += 256)
            psumB[(size_t)bi * 256 + j] = sds[j];
    }
}

// Reduce scan1 partials -> s_j (coalesced), then c_j = scale_j * K_{j%2} @ s_j.
__global__ void k_cvec(const float* __restrict__ rel,
                       const float* __restrict__ psumA, const float* __restrict__ psumB,
                       float* __restrict__ cvec) {
    const int j = blockIdx.x;        // 0..5: pos0,pos1,nh0,nh1,nt0,nt1
    const int tid = threadIdx.x;     // 256
    const int g = tid >> 7, i = tid & 127;
    __shared__ float red[256];
    __shared__ float sv[D];

    float s = 0.f;
    if (j == 1 || j == 5) {
        const int plane = (j == 1) ? 0 : 1;
        for (int b = g; b < GB; b += 2) s += psumB[(size_t)b * 256 + plane * D + i];
    } else {
        const int plane = (j == 0) ? 0 : (j - 1);
        for (int b = g; b < GA; b += 2) s += psumA[(size_t)b * 512 + plane * D + i];
    }
    red[tid] = s;
    __syncthreads();
    if (tid < 128) sv[i] = red[i] + red[128 + i];
    __syncthreads();

    if (tid < 128) {
        const float* Kp = rel + (size_t)(j & 1) * D * D;
        const float scale = (j == 2 || j == 3) ? (float)S_NEG : 1.0f;
        float acc = 0.f;
#pragma unroll 8
        for (int k = 0; k < D; ++k) acc += Kp[(size_t)i * D + k] * sv[k];
        cvec[j * D + i] = acc * scale;
    }
}

// PA[n*5+k] = emb_A[n].c_k (k=0..4);  PB[n] = emb_B[n].c_5
__global__ void k_scan2(const float* __restrict__ embA, const float* __restrict__ embB,
                        const float* __restrict__ cvec, float* __restrict__ PA,
                        float* __restrict__ PB) {
    __shared__ float sc[5 * D];
    const int tid = threadIdx.x;
    const int l = tid & 31;
    const int grp = tid >> 5;

    if ((int)blockIdx.x < GA) {
        for (int j = tid; j < 5 * D; j += 256) sc[j] = cvec[j];  // c0..c4
        __syncthreads();
        for (int n = blockIdx.x * 8 + grp; n < N_A; n += GA * 8) {
            const float4 r = *reinterpret_cast<const float4*>(embA + (size_t)n * D + 4 * l);
            float p0 = r.x*sc[0*D+4*l] + r.y*sc[0*D+4*l+1] + r.z*sc[0*D+4*l+2] + r.w*sc[0*D+4*l+3];
            float p1 = r.x*sc[1*D+4*l] + r.y*sc[1*D+4*l+1] + r.z*sc[1*D+4*l+2] + r.w*sc[1*D+4*l+3];
            float p2 = r.x*sc[2*D+4*l] + r.y*sc[2*D+4*l+1] + r.z*sc[2*D+4*l+2] + r.w*sc[2*D+4*l+3];
            float p3 = r.x*sc[3*D+4*l] + r.y*sc[3*D+4*l+1] + r.z*sc[3*D+4*l+2] + r.w*sc[3*D+4*l+3];
            float p4 = r.x*sc[4*D+4*l] + r.y*sc[4*D+4*l+1] + r.z*sc[4*D+4*l+2] + r.w*sc[4*D+4*l+3];
#pragma unroll
            for (int m = 1; m <= 16; m <<= 1) {
                p0 += __shfl_xor(p0, m);
                p1 += __shfl_xor(p1, m);
                p2 += __shfl_xor(p2, m);
                p3 += __shfl_xor(p3, m);
                p4 += __shfl_xor(p4, m);
            }
            if (l == 0) {
                float* o = PA + (size_t)n * 5;
                o[0] = p0; o[1] = p1; o[2] = p2; o[3] = p3; o[4] = p4;
            }
        }
    } else {
        for (int j = tid; j < D; j += 256) sc[j] = cvec[5 * D + j];  // c5
        __syncthreads();
        const int bi = blockIdx.x - GA;
        for (int n = bi * 8 + grp; n < N_B; n += GB * 8) {
            const float4 r = *reinterpret_cast<const float4*>(embB + (size_t)n * D + 4 * l);
            float p = r.x*sc[4*l] + r.y*sc[4*l+1] + r.z*sc[4*l+2] + r.w*sc[4*l+3];
#pragma unroll
            for (int m = 1; m <= 16; m <<= 1) p += __shfl_xor(p, m);
            if (l == 0) PB[n] = p;
        }
    }
}

__global__ void k_scatter(const int* __restrict__ ei0, const int* __restrict__ ei1,
                          const int* __restrict__ nh0, const int* __restrict__ nh1,
                          const int* __restrict__ nt0, const int* __restrict__ nt1,
                          const float* __restrict__ PA, const float* __restrict__ PB,
                          float* __restrict__ out) {
    const int total = 2 * E_EDGES + 4 * ES;  // 3.3M
    for (int t = blockIdx.x * blockDim.x + threadIdx.x; t < total;
         t += gridDim.x * blockDim.x) {
        float v;
        if (t < E_EDGES) {
            v = PA[(size_t)ei0[t] * 5 + 0];                               // pos0
        } else if (t < 2 * E_EDGES) {
            v = PA[(size_t)ei1[t - E_EDGES] * 5 + 1];                     // pos1
        } else if (t < 2 * E_EDGES + ES) {
            v = PA[(size_t)nh0[t - 2 * E_EDGES] * 5 + 2];                 // nh0
        } else if (t < 2 * E_EDGES + 2 * ES) {
            v = PA[(size_t)nh1[t - 2 * E_EDGES - ES] * 5 + 3];            // nh1
        } else if (t < 2 * E_EDGES + 3 * ES) {
            const int i = t - 2 * E_EDGES - 2 * ES;
            v = PA[(size_t)nt0[(i >> 4) << 4] * 5 + 4];                   // nt0 (repeat S)
        } else {
            const int i = t - 2 * E_EDGES - 3 * ES;
            v = PB[nt1[(i >> 4) << 4]];                                   // nt1 (repeat S)
        }
        out[t] = v;
    }
}

extern "C" void kernel_launch(void* const* d_in, const int* in_sizes, int n_in,
                              void* d_out, int out_size, void* d_ws, size_t ws_size,
                              hipStream_t stream) {
    const float* embA = (const float*)d_in[0];
    const float* embB = (const float*)d_in[1];
    const float* rel  = (const float*)d_in[2];
    const int* ei0 = (const int*)d_in[3];
    const int* ei1 = (const int*)d_in[4];
    const int* nh0 = (const int*)d_in[5];
    const int* nh1 = (const int*)d_in[6];
    const int* nt0 = (const int*)d_in[7];
    const int* nt1 = (const int*)d_in[8];
    float* out = (float*)d_out;

    uint32_t* partA = (uint32_t*)d_ws;                        // 152*CHUNK
    uint32_t* partB = partA + (size_t)152 * CHUNK;            // 68*CHUNK
    int4* cntAi = (int4*)(partB + (size_t)B_SLABS * CHUNK);   // N_A int4
    int2* cntBi = (int2*)(cntAi + N_A);                       // N_B int2
    float* psumA = (float*)(cntBi + N_B);                     // GA*512
    float* psumB = psumA + (size_t)GA * 512;                  // GB*256
    float* cvec  = psumB + (size_t)GB * 256;                  // 6*D
    float* PA    = cvec + 6 * D;                              // N_A*5
    float* PB    = PA + (size_t)N_A * 5;                      // N_B

    k_hist<<<220, 256, 0, stream>>>(ei0, ei1, nh0, nh1, nt0, nt1, partA, partB);
    k_reduceC<<<(N_A + N_B + 255) / 256, 256, 0, stream>>>(partA, partB, cntAi, cntBi);
    k_scan1<<<GA + GB, 256, 0, stream>>>(embA, embB, cntAi, cntBi, psumA, psumB);
    k_cvec<<<6, 256, 0, stream>>>(rel, psumA, psumB, cvec);
    k_scan2<<<GA + GB, 256, 0, stream>>>(embA, embB, cvec, PA, PB);
    k_scatter<<<4096, 256, 0, stream>>>(ei0, ei1, nh0, nh1, nt0, nt1, PA, PB, out);
}

// Round 4
// 233.177 us; speedup vs baseline: 1.7128x; 1.7128x over previous
//
#include <hip/hip_runtime.h>
#include <stdint.h>

#define D 128
#define E_EDGES 50000
#define S_NEG 16
#define N_A 100000
#define N_B 50000
#define ES (E_EDGES * S_NEG)

#define CHUNK 12500   // items per hist block; also words per hist slab
#define B_SLABS 68    // B slabs: B0:0-3, B1:4-67
#define GA 1344       // scan blocks for the A table (= 42 * 32)
#define GB 704        // scan blocks for the B table (= 22 * 32); GA+GB = 2048
#define RA 42         // stage-1-reduced A partials
#define RB 22         // stage-1-reduced B partials

// ---------------------------------------------------------------------------
// ws layout (4-byte words):
//   u32 partA[152 * CHUNK]  byte-hist slabs, slab = (chunkcol*2 + half)
//   u32 partB[ 68 * CHUNK]
//   int4 cntAi[N_A]         per-row counts {pos0, nh0, nh1, nt0}
//   int2 cntBi[N_B]         per-row counts {pos1, nt1}
//   f32 psumA[GA * 512]     scan1 per-block partials [plane0..3][128]
//   f32 psumB[GB * 256]
//   f32 psumA2[RA * 512]    stage-1 reduced partials
//   f32 psumB2[RB * 256]
//   f32 cvec[6 * D]
//   f32 PA[N_A * 5],  f32 PB[N_B]
// ---------------------------------------------------------------------------

__global__ void k_hist(const int* __restrict__ ei0, const int* __restrict__ ei1,
                       const int* __restrict__ nh0, const int* __restrict__ nh1,
                       const int* __restrict__ nt0, const int* __restrict__ nt1,
                       uint32_t* __restrict__ partA, uint32_t* __restrict__ partB) {
    __shared__ uint32_t h[CHUNK];
    const int tid = threadIdx.x;
    for (int w = tid; w < CHUNK; w += 256) h[w] = 0;
    __syncthreads();

    const int b = blockIdx.x;
    const int* src; long long base; int stride, lo; uint32_t* dst;
    if (b < 8) {                       // A0: pos0 tails = ei0[E..2E)
        const int c = b >> 1, hh = b & 1;
        src = ei0; base = E_EDGES + (long long)c * CHUNK; stride = 1;
        lo = hh * 50000; dst = partA + (size_t)(c * 2 + hh) * CHUNK;
    } else if (b < 16) {               // A1: nh0 column 0
        const int q = b - 8, c = q >> 1, hh = q & 1;
        src = nh0; base = (long long)c * CHUNK * S_NEG; stride = S_NEG;
        lo = hh * 50000; dst = partA + (size_t)((4 + c) * 2 + hh) * CHUNK;
    } else if (b < 24) {               // A2: nh1 column 0
        const int q = b - 16, c = q >> 1, hh = q & 1;
        src = nh1; base = (long long)c * CHUNK * S_NEG; stride = S_NEG;
        lo = hh * 50000; dst = partA + (size_t)((8 + c) * 2 + hh) * CHUNK;
    } else if (b < 152) {              // A3: nt0 flat (800k, 64 chunks x 2 halves)
        const int q = b - 24, c = q >> 1, hh = q & 1;
        src = nt0; base = (long long)c * CHUNK; stride = 1;
        lo = hh * 50000; dst = partA + (size_t)((12 + c) * 2 + hh) * CHUNK;
    } else if (b < 156) {              // B0: pos1 tails = ei1[E..2E)
        const int c = b - 152;
        src = ei1; base = E_EDGES + (long long)c * CHUNK; stride = 1;
        lo = 0; dst = partB + (size_t)c * CHUNK;
    } else {                           // B1: nt1 flat (800k, 64 chunks)
        const int c = b - 156;
        src = nt1; base = (long long)c * CHUNK; stride = 1;
        lo = 0; dst = partB + (size_t)(4 + c) * CHUNK;
    }

    for (int i = tid; i < CHUNK; i += 256) {
        const unsigned r = (unsigned)(src[base + (long long)i * stride] - lo);
        if (r < 50000u) atomicAdd(&h[r >> 2], 1u << ((r & 3u) * 8u));
    }
    __syncthreads();
    for (int w = tid; w < CHUNK; w += 256) dst[w] = h[w];
}

// thread-per-bin: sum the byte partials -> interleaved int counts.
__global__ void k_reduceC(const uint32_t* __restrict__ partA,
                          const uint32_t* __restrict__ partB,
                          int4* __restrict__ cntAi, int2* __restrict__ cntBi) {
    const int t = blockIdx.x * 256 + threadIdx.x;
    if (t < N_A) {
        const int n = t;
        const int hh = (n >= 50000);
        const int w = (n - hh * 50000) >> 2;
        const int sh = (n & 3) * 8;
        const uint32_t* p = partA + (size_t)hh * CHUNK + w;
        unsigned s0 = 0, s1 = 0, s2 = 0, s3 = 0;
#pragma unroll
        for (int c = 0; c < 4; ++c)   s0 += (p[(size_t)(c * 2) * CHUNK] >> sh) & 255u;
#pragma unroll
        for (int c = 4; c < 8; ++c)   s1 += (p[(size_t)(c * 2) * CHUNK] >> sh) & 255u;
#pragma unroll
        for (int c = 8; c < 12; ++c)  s2 += (p[(size_t)(c * 2) * CHUNK] >> sh) & 255u;
#pragma unroll 8
        for (int c = 12; c < 76; ++c) s3 += (p[(size_t)(c * 2) * CHUNK] >> sh) & 255u;
        cntAi[n] = make_int4((int)s0, (int)s1, (int)s2, (int)s3);
    } else if (t < N_A + N_B) {
        const int n = t - N_A;
        const int w = n >> 2;
        const int sh = (n & 3) * 8;
        const uint32_t* p = partB + w;
        unsigned s0 = 0, s1 = 0;
#pragma unroll
        for (int c = 0; c < 4; ++c)   s0 += (p[(size_t)c * CHUNK] >> sh) & 255u;
#pragma unroll 8
        for (int c = 4; c < 68; ++c)  s1 += (p[(size_t)c * CHUNK] >> sh) & 255u;
        cntBi[n] = make_int2((int)s0, (int)s1);
    }
}

// Weighted table scan: per-block partial s_j written dense.
__global__ void k_scan1(const float* __restrict__ embA, const float* __restrict__ embB,
                        const int4* __restrict__ cntAi, const int2* __restrict__ cntBi,
                        float* __restrict__ psumA, float* __restrict__ psumB) {
    __shared__ float sds[4 * D];
    const int tid = threadIdx.x;
    const int l = tid & 31;
    const int grp = tid >> 5;  // 0..7

    for (int j = tid; j < 4 * D; j += 256) sds[j] = 0.f;
    __syncthreads();

    if ((int)blockIdx.x < GA) {
        float a0=0,a1=0,a2=0,a3=0, b0=0,b1=0,b2=0,b3=0;
        float c0=0,c1=0,c2=0,c3=0, d0=0,d1=0,d2=0,d3=0;
        for (int n = blockIdx.x * 8 + grp; n < N_A; n += GA * 8) {
            const int4 w = cntAi[n];
            const float4 r = *reinterpret_cast<const float4*>(embA + (size_t)n * D + 4 * l);
            float f;
            f = (float)w.x; a0 += f*r.x; a1 += f*r.y; a2 += f*r.z; a3 += f*r.w;
            f = (float)w.y; b0 += f*r.x; b1 += f*r.y; b2 += f*r.z; b3 += f*r.w;
            f = (float)w.z; c0 += f*r.x; c1 += f*r.y; c2 += f*r.z; c3 += f*r.w;
            f = (float)w.w; d0 += f*r.x; d1 += f*r.y; d2 += f*r.z; d3 += f*r.w;
        }
        atomicAdd(&sds[0*D + 4*l+0], a0); atomicAdd(&sds[0*D + 4*l+1], a1);
        atomicAdd(&sds[0*D + 4*l+2], a2); atomicAdd(&sds[0*D + 4*l+3], a3);
        atomicAdd(&sds[1*D + 4*l+0], b0); atomicAdd(&sds[1*D + 4*l+1], b1);
        atomicAdd(&sds[1*D + 4*l+2], b2); atomicAdd(&sds[1*D + 4*l+3], b3);
        atomicAdd(&sds[2*D + 4*l+0], c0); atomicAdd(&sds[2*D + 4*l+1], c1);
        atomicAdd(&sds[2*D + 4*l+2], c2); atomicAdd(&sds[2*D + 4*l+3], c3);
        atomicAdd(&sds[3*D + 4*l+0], d0); atomicAdd(&sds[3*D + 4*l+1], d1);
        atomicAdd(&sds[3*D + 4*l+2], d2); atomicAdd(&sds[3*D + 4*l+3], d3);
        __syncthreads();
        for (int j = tid; j < 4 * D; j += 256)
            psumA[(size_t)blockIdx.x * 512 + j] = sds[j];
    } else {
        const int bi = blockIdx.x - GA;
        float a0=0,a1=0,a2=0,a3=0, b0=0,b1=0,b2=0,b3=0;
        for (int n = bi * 8 + grp; n < N_B; n += GB * 8) {
            const int2 w = cntBi[n];
            const float4 r = *reinterpret_cast<const float4*>(embB + (size_t)n * D + 4 * l);
            float f;
            f = (float)w.x; a0 += f*r.x; a1 += f*r.y; a2 += f*r.z; a3 += f*r.w;
            f = (float)w.y; b0 += f*r.x; b1 += f*r.y; b2 += f*r.z; b3 += f*r.w;
        }
        atomicAdd(&sds[0*D + 4*l+0], a0); atomicAdd(&sds[0*D + 4*l+1], a1);
        atomicAdd(&sds[0*D + 4*l+2], a2); atomicAdd(&sds[0*D + 4*l+3], a3);
        atomicAdd(&sds[1*D + 4*l+0], b0); atomicAdd(&sds[1*D + 4*l+1], b1);
        atomicAdd(&sds[1*D + 4*l+2], b2); atomicAdd(&sds[1*D + 4*l+3], b3);
        __syncthreads();
        for (int j = tid; j < 2 * D; j += 256)
            psumB[(size_t)bi * 256 + j] = sds[j];
    }
}

// Stage-1 tree reduce of scan1 partials: 32 rows per block, coalesced.
__global__ void k_red1(const float* __restrict__ psumA, const float* __restrict__ psumB,
                       float* __restrict__ psumA2, float* __restrict__ psumB2) {
    const int b = blockIdx.x, t = threadIdx.x;
    if (b < RA) {
        const float* p = psumA + (size_t)b * 32 * 512;
        float s0 = 0.f, s1 = 0.f;
#pragma unroll 8
        for (int r = 0; r < 32; ++r) { s0 += p[r * 512 + t]; s1 += p[r * 512 + 256 + t]; }
        psumA2[(size_t)b * 512 + t] = s0;
        psumA2[(size_t)b * 512 + 256 + t] = s1;
    } else {
        const int bi = b - RA;
        const float* p = psumB + (size_t)bi * 32 * 256;
        float s = 0.f;
#pragma unroll 8
        for (int r = 0; r < 32; ++r) s += p[r * 256 + t];
        psumB2[(size_t)bi * 256 + t] = s;
    }
}

// Final reduce (42/22 partials) -> s_j; then c_j = scale_j * K_{j%2} @ s_j.
__global__ void k_cvec2(const float* __restrict__ rel,
                        const float* __restrict__ psumA2, const float* __restrict__ psumB2,
                        float* __restrict__ cvec) {
    const int j = blockIdx.x;        // 0..5: pos0,pos1,nh0,nh1,nt0,nt1
    const int tid = threadIdx.x;     // 256
    const int g = tid >> 7, i = tid & 127;
    __shared__ float red[256];
    __shared__ float sv[D];

    float s = 0.f;
    if (j == 1 || j == 5) {
        const int plane = (j == 1) ? 0 : 1;
        for (int b = g; b < RB; b += 2) s += psumB2[(size_t)b * 256 + plane * D + i];
    } else {
        const int plane = (j == 0) ? 0 : (j - 1);
        for (int b = g; b < RA; b += 2) s += psumA2[(size_t)b * 512 + plane * D + i];
    }
    red[tid] = s;
    __syncthreads();
    if (tid < 128) sv[i] = red[i] + red[128 + i];
    __syncthreads();

    if (tid < 128) {
        const float* Kp = rel + (size_t)(j & 1) * D * D;
        const float scale = (j == 2 || j == 3) ? (float)S_NEG : 1.0f;
        float acc = 0.f;
#pragma unroll 8
        for (int k = 0; k < D; ++k) acc += Kp[(size_t)i * D + k] * sv[k];
        cvec[j * D + i] = acc * scale;
    }
}

// PA[n*5+k] = emb_A[n].c_k (k=0..4);  PB[n] = emb_B[n].c_5
__global__ void k_scan2(const float* __restrict__ embA, const float* __restrict__ embB,
                        const float* __restrict__ cvec, float* __restrict__ PA,
                        float* __restrict__ PB) {
    __shared__ float sc[5 * D];
    const int tid = threadIdx.x;
    const int l = tid & 31;
    const int grp = tid >> 5;

    if ((int)blockIdx.x < GA) {
        for (int j = tid; j < 5 * D; j += 256) sc[j] = cvec[j];  // c0..c4
        __syncthreads();
        for (int n = blockIdx.x * 8 + grp; n < N_A; n += GA * 8) {
            const float4 r = *reinterpret_cast<const float4*>(embA + (size_t)n * D + 4 * l);
            float p0 = r.x*sc[0*D+4*l] + r.y*sc[0*D+4*l+1] + r.z*sc[0*D+4*l+2] + r.w*sc[0*D+4*l+3];
            float p1 = r.x*sc[1*D+4*l] + r.y*sc[1*D+4*l+1] + r.z*sc[1*D+4*l+2] + r.w*sc[1*D+4*l+3];
            float p2 = r.x*sc[2*D+4*l] + r.y*sc[2*D+4*l+1] + r.z*sc[2*D+4*l+2] + r.w*sc[2*D+4*l+3];
            float p3 = r.x*sc[3*D+4*l] + r.y*sc[3*D+4*l+1] + r.z*sc[3*D+4*l+2] + r.w*sc[3*D+4*l+3];
            float p4 = r.x*sc[4*D+4*l] + r.y*sc[4*D+4*l+1] + r.z*sc[4*D+4*l+2] + r.w*sc[4*D+4*l+3];
#pragma unroll
            for (int m = 1; m <= 16; m <<= 1) {
                p0 += __shfl_xor(p0, m);
                p1 += __shfl_xor(p1, m);
                p2 += __shfl_xor(p2, m);
                p3 += __shfl_xor(p3, m);
                p4 += __shfl_xor(p4, m);
            }
            if (l == 0) {
                float* o = PA + (size_t)n * 5;
                o[0] = p0; o[1] = p1; o[2] = p2; o[3] = p3; o[4] = p4;
            }
        }
    } else {
        for (int j = tid; j < D; j += 256) sc[j] = cvec[5 * D + j];  // c5
        __syncthreads();
        const int bi = blockIdx.x - GA;
        for (int n = bi * 8 + grp; n < N_B; n += GB * 8) {
            const float4 r = *reinterpret_cast<const float4*>(embB + (size_t)n * D + 4 * l);
            float p = r.x*sc[4*l] + r.y*sc[4*l+1] + r.z*sc[4*l+2] + r.w*sc[4*l+3];
#pragma unroll
            for (int m = 1; m <= 16; m <<= 1) p += __shfl_xor(p, m);
            if (l == 0) PB[n] = p;
        }
    }
}

__global__ void k_scatter(const int* __restrict__ ei0, const int* __restrict__ ei1,
                          const int* __restrict__ nh0, const int* __restrict__ nh1,
                          const int* __restrict__ nt0, const int* __restrict__ nt1,
                          const float* __restrict__ PA, const float* __restrict__ PB,
                          float* __restrict__ out) {
    const int total = 2 * E_EDGES + 4 * ES;  // 3.3M
    for (int t = blockIdx.x * blockDim.x + threadIdx.x; t < total;
         t += gridDim.x * blockDim.x) {
        float v;
        if (t < E_EDGES) {
            v = PA[(size_t)ei0[t] * 5 + 0];                               // pos0
        } else if (t < 2 * E_EDGES) {
            v = PA[(size_t)ei1[t - E_EDGES] * 5 + 1];                     // pos1
        } else if (t < 2 * E_EDGES + ES) {
            v = PA[(size_t)nh0[t - 2 * E_EDGES] * 5 + 2];                 // nh0
        } else if (t < 2 * E_EDGES + 2 * ES) {
            v = PA[(size_t)nh1[t - 2 * E_EDGES - ES] * 5 + 3];            // nh1
        } else if (t < 2 * E_EDGES + 3 * ES) {
            const int i = t - 2 * E_EDGES - 2 * ES;
            v = PA[(size_t)nt0[(i >> 4) << 4] * 5 + 4];                   // nt0 (repeat S)
        } else {
            const int i = t - 2 * E_EDGES - 3 * ES;
            v = PB[nt1[(i >> 4) << 4]];                                   // nt1 (repeat S)
        }
        out[t] = v;
    }
}

extern "C" void kernel_launch(void* const* d_in, const int* in_sizes, int n_in,
                              void* d_out, int out_size, void* d_ws, size_t ws_size,
                              hipStream_t stream) {
    const float* embA = (const float*)d_in[0];
    const float* embB = (const float*)d_in[1];
    const float* rel  = (const float*)d_in[2];
    const int* ei0 = (const int*)d_in[3];
    const int* ei1 = (const int*)d_in[4];
    const int* nh0 = (const int*)d_in[5];
    const int* nh1 = (const int*)d_in[6];
    const int* nt0 = (const int*)d_in[7];
    const int* nt1 = (const int*)d_in[8];
    float* out = (float*)d_out;

    uint32_t* partA = (uint32_t*)d_ws;                        // 152*CHUNK
    uint32_t* partB = partA + (size_t)152 * CHUNK;            // 68*CHUNK
    int4* cntAi = (int4*)(partB + (size_t)B_SLABS * CHUNK);   // N_A int4
    int2* cntBi = (int2*)(cntAi + N_A);                       // N_B int2
    float* psumA = (float*)(cntBi + N_B);                     // GA*512
    float* psumB = psumA + (size_t)GA * 512;                  // GB*256
    float* psumA2 = psumB + (size_t)GB * 256;                 // RA*512
    float* psumB2 = psumA2 + (size_t)RA * 512;                // RB*256
    float* cvec  = psumB2 + (size_t)RB * 256;                 // 6*D
    float* PA    = cvec + 6 * D;                              // N_A*5
    float* PB    = PA + (size_t)N_A * 5;                      // N_B

    k_hist<<<220, 256, 0, stream>>>(ei0, ei1, nh0, nh1, nt0, nt1, partA, partB);
    k_reduceC<<<(N_A + N_B + 255) / 256, 256, 0, stream>>>(partA, partB, cntAi, cntBi);
    k_scan1<<<GA + GB, 256, 0, stream>>>(embA, embB, cntAi, cntBi, psumA, psumB);
    k_red1<<<RA + RB, 256, 0, stream>>>(psumA, psumB, psumA2, psumB2);
    k_cvec2<<<6, 256, 0, stream>>>(rel, psumA2, psumB2, cvec);
    k_scan2<<<GA + GB, 256, 0, stream>>>(embA, embB, cvec, PA, PB);
    k_scatter<<<4096, 256, 0, stream>>>(ei0, ei1, nh0, nh1, nt0, nt1, PA, PB, out);
}

// Round 5
// 214.698 us; speedup vs baseline: 1.8602x; 1.0861x over previous
//
#include <hip/hip_runtime.h>
#include <stdint.h>

#define D 128
#define E_EDGES 50000
#define S_NEG 16
#define N_A 100000
#define N_B 50000
#define ES (E_EDGES * S_NEG)

#define CHUNK 12500   // items per hist block; also words per hist slab
#define B_SLABS 68    // B slabs: B0:0-3, B1:4-67
#define GA 512        // scan blocks for the A table (4096 groups)
#define GB 256        // scan blocks for the B table (2048 groups)
#define RPG 25        // contiguous rows per group (4096*25>=100000, 2048*25>=50000)
#define RA 16         // stage-1-reduced A partials (16*32 = 512 = GA)
#define RB 8          // stage-1-reduced B partials (8*32 = 256 = GB)

__device__ inline float dot4(float4 a, float4 b) {
    return a.x * b.x + a.y * b.y + a.z * b.z + a.w * b.w;
}
#define RED32(p) { p += __shfl_xor(p, 1); p += __shfl_xor(p, 2); p += __shfl_xor(p, 4); \
                   p += __shfl_xor(p, 8); p += __shfl_xor(p, 16); }

// ---------------------------------------------------------------------------
// ws layout (4-byte words):
//   u32    partA[152 * CHUNK], partB[68 * CHUNK]   byte-hist slabs
//   float4 cwA[N_A]   per-row float counts {pos0, nh0, nh1, nt0}
//   float2 cwB[N_B]   per-row float counts {pos1, nt1}
//   f32 psumA[GA*512], psumB[GB*256]    scan1 per-block partials
//   f32 psumA2[RA*512], psumB2[RB*256]  stage-1 reduced
//   f32 cvec[6*D];  f32 PA[N_A*5];  f32 PB[N_B]
// ---------------------------------------------------------------------------

__global__ void k_hist(const int* __restrict__ ei0, const int* __restrict__ ei1,
                       const int* __restrict__ nh0, const int* __restrict__ nh1,
                       const int* __restrict__ nt0, const int* __restrict__ nt1,
                       uint32_t* __restrict__ partA, uint32_t* __restrict__ partB) {
    __shared__ uint32_t h[CHUNK];
    const int tid = threadIdx.x;
    for (int w = tid; w < CHUNK; w += 256) h[w] = 0;
    __syncthreads();

    const int b = blockIdx.x;
    const int* src; long long base; int stride, lo; uint32_t* dst;
    if (b < 8) {                       // A0: pos0 tails = ei0[E..2E)
        const int c = b >> 1, hh = b & 1;
        src = ei0; base = E_EDGES + (long long)c * CHUNK; stride = 1;
        lo = hh * 50000; dst = partA + (size_t)(c * 2 + hh) * CHUNK;
    } else if (b < 16) {               // A1: nh0 column 0
        const int q = b - 8, c = q >> 1, hh = q & 1;
        src = nh0; base = (long long)c * CHUNK * S_NEG; stride = S_NEG;
        lo = hh * 50000; dst = partA + (size_t)((4 + c) * 2 + hh) * CHUNK;
    } else if (b < 24) {               // A2: nh1 column 0
        const int q = b - 16, c = q >> 1, hh = q & 1;
        src = nh1; base = (long long)c * CHUNK * S_NEG; stride = S_NEG;
        lo = hh * 50000; dst = partA + (size_t)((8 + c) * 2 + hh) * CHUNK;
    } else if (b < 152) {              // A3: nt0 flat (800k, 64 chunks x 2 halves)
        const int q = b - 24, c = q >> 1, hh = q & 1;
        src = nt0; base = (long long)c * CHUNK; stride = 1;
        lo = hh * 50000; dst = partA + (size_t)((12 + c) * 2 + hh) * CHUNK;
    } else if (b < 156) {              // B0: pos1 tails = ei1[E..2E)
        const int c = b - 152;
        src = ei1; base = E_EDGES + (long long)c * CHUNK; stride = 1;
        lo = 0; dst = partB + (size_t)c * CHUNK;
    } else {                           // B1: nt1 flat (800k, 64 chunks)
        const int c = b - 156;
        src = nt1; base = (long long)c * CHUNK; stride = 1;
        lo = 0; dst = partB + (size_t)(4 + c) * CHUNK;
    }

    for (int i = tid; i < CHUNK; i += 256) {
        const unsigned r = (unsigned)(src[base + (long long)i * stride] - lo);
        if (r < 50000u) atomicAdd(&h[r >> 2], 1u << ((r & 3u) * 8u));
    }
    __syncthreads();
    for (int w = tid; w < CHUNK; w += 256) dst[w] = h[w];
}

// thread-per-bin: sum byte partials -> FLOAT counts (FMA-ready in scan1).
__global__ void k_reduceC(const uint32_t* __restrict__ partA,
                          const uint32_t* __restrict__ partB,
                          float4* __restrict__ cwA, float2* __restrict__ cwB) {
    const int t = blockIdx.x * 256 + threadIdx.x;
    if (t < N_A) {
        const int n = t;
        const int hh = (n >= 50000);
        const int w = (n - hh * 50000) >> 2;
        const int sh = (n & 3) * 8;
        const uint32_t* p = partA + (size_t)hh * CHUNK + w;
        unsigned s0 = 0, s1 = 0, s2 = 0, s3 = 0;
#pragma unroll
        for (int c = 0; c < 4; ++c)   s0 += (p[(size_t)(c * 2) * CHUNK] >> sh) & 255u;
#pragma unroll
        for (int c = 4; c < 8; ++c)   s1 += (p[(size_t)(c * 2) * CHUNK] >> sh) & 255u;
#pragma unroll
        for (int c = 8; c < 12; ++c)  s2 += (p[(size_t)(c * 2) * CHUNK] >> sh) & 255u;
#pragma unroll 8
        for (int c = 12; c < 76; ++c) s3 += (p[(size_t)(c * 2) * CHUNK] >> sh) & 255u;
        cwA[n] = make_float4((float)s0, (float)s1, (float)s2, (float)s3);
    } else if (t < N_A + N_B) {
        const int n = t - N_A;
        const int w = n >> 2;
        const int sh = (n & 3) * 8;
        const uint32_t* p = partB + w;
        unsigned s0 = 0, s1 = 0;
#pragma unroll
        for (int c = 0; c < 4; ++c)   s0 += (p[(size_t)c * CHUNK] >> sh) & 255u;
#pragma unroll 8
        for (int c = 4; c < 68; ++c)  s1 += (p[(size_t)c * CHUNK] >> sh) & 255u;
        cwB[n] = make_float2((float)s0, (float)s1);
    }
}

// Weighted table scan, 4-row unroll (8 independent loads in flight per iter).
__global__ void k_scan1(const float* __restrict__ embA, const float* __restrict__ embB,
                        const float4* __restrict__ cwA, const float2* __restrict__ cwB,
                        float* __restrict__ psumA, float* __restrict__ psumB) {
    __shared__ float sds[4 * D];
    const int tid = threadIdx.x;
    const int l = tid & 31;
    const int grp = tid >> 5;

    for (int j = tid; j < 4 * D; j += 256) sds[j] = 0.f;
    __syncthreads();

    if ((int)blockIdx.x < GA) {
        const int gid = blockIdx.x * 8 + grp;
        int r = gid * RPG;
        const int end = min(r + RPG, N_A);
        float acc[16];
#pragma unroll
        for (int k = 0; k < 16; ++k) acc[k] = 0.f;
        const float* base = embA + 4 * l;
        for (; r + 4 <= end; r += 4) {
            float4 w[4], x[4];
#pragma unroll
            for (int u = 0; u < 4; ++u) w[u] = cwA[r + u];
#pragma unroll
            for (int u = 0; u < 4; ++u)
                x[u] = *reinterpret_cast<const float4*>(base + (size_t)(r + u) * D);
#pragma unroll
            for (int u = 0; u < 4; ++u) {
                acc[0]  += w[u].x * x[u].x; acc[1]  += w[u].x * x[u].y;
                acc[2]  += w[u].x * x[u].z; acc[3]  += w[u].x * x[u].w;
                acc[4]  += w[u].y * x[u].x; acc[5]  += w[u].y * x[u].y;
                acc[6]  += w[u].y * x[u].z; acc[7]  += w[u].y * x[u].w;
                acc[8]  += w[u].z * x[u].x; acc[9]  += w[u].z * x[u].y;
                acc[10] += w[u].z * x[u].z; acc[11] += w[u].z * x[u].w;
                acc[12] += w[u].w * x[u].x; acc[13] += w[u].w * x[u].y;
                acc[14] += w[u].w * x[u].z; acc[15] += w[u].w * x[u].w;
            }
        }
        for (; r < end; ++r) {
            const float4 w0 = cwA[r];
            const float4 x0 = *reinterpret_cast<const float4*>(base + (size_t)r * D);
            acc[0]  += w0.x * x0.x; acc[1]  += w0.x * x0.y; acc[2]  += w0.x * x0.z; acc[3]  += w0.x * x0.w;
            acc[4]  += w0.y * x0.x; acc[5]  += w0.y * x0.y; acc[6]  += w0.y * x0.z; acc[7]  += w0.y * x0.w;
            acc[8]  += w0.z * x0.x; acc[9]  += w0.z * x0.y; acc[10] += w0.z * x0.z; acc[11] += w0.z * x0.w;
            acc[12] += w0.w * x0.x; acc[13] += w0.w * x0.y; acc[14] += w0.w * x0.z; acc[15] += w0.w * x0.w;
        }
#pragma unroll
        for (int p = 0; p < 4; ++p)
#pragma unroll
            for (int k = 0; k < 4; ++k)
                atomicAdd(&sds[p * D + 4 * l + k], acc[p * 4 + k]);
        __syncthreads();
        for (int j = tid; j < 4 * D; j += 256)
            psumA[(size_t)blockIdx.x * 512 + j] = sds[j];
    } else {
        const int gid = (blockIdx.x - GA) * 8 + grp;
        int r = gid * RPG;
        const int end = min(r + RPG, N_B);
        float acc[8];
#pragma unroll
        for (int k = 0; k < 8; ++k) acc[k] = 0.f;
        const float* base = embB + 4 * l;
        for (; r + 4 <= end; r += 4) {
            float2 w[4]; float4 x[4];
#pragma unroll
            for (int u = 0; u < 4; ++u) w[u] = cwB[r + u];
#pragma unroll
            for (int u = 0; u < 4; ++u)
                x[u] = *reinterpret_cast<const float4*>(base + (size_t)(r + u) * D);
#pragma unroll
            for (int u = 0; u < 4; ++u) {
                acc[0] += w[u].x * x[u].x; acc[1] += w[u].x * x[u].y;
                acc[2] += w[u].x * x[u].z; acc[3] += w[u].x * x[u].w;
                acc[4] += w[u].y * x[u].x; acc[5] += w[u].y * x[u].y;
                acc[6] += w[u].y * x[u].z; acc[7] += w[u].y * x[u].w;
            }
        }
        for (; r < end; ++r) {
            const float2 w0 = cwB[r];
            const float4 x0 = *reinterpret_cast<const float4*>(base + (size_t)r * D);
            acc[0] += w0.x * x0.x; acc[1] += w0.x * x0.y; acc[2] += w0.x * x0.z; acc[3] += w0.x * x0.w;
            acc[4] += w0.y * x0.x; acc[5] += w0.y * x0.y; acc[6] += w0.y * x0.z; acc[7] += w0.y * x0.w;
        }
#pragma unroll
        for (int p = 0; p < 2; ++p)
#pragma unroll
            for (int k = 0; k < 4; ++k)
                atomicAdd(&sds[p * D + 4 * l + k], acc[p * 4 + k]);
        __syncthreads();
        for (int j = tid; j < 2 * D; j += 256)
            psumB[(size_t)(blockIdx.x - GA) * 256 + j] = sds[j];
    }
}

// Stage-1 tree reduce: 32 psum rows per block, coalesced.
__global__ void k_red1(const float* __restrict__ psumA, const float* __restrict__ psumB,
                       float* __restrict__ psumA2, float* __restrict__ psumB2) {
    const int b = blockIdx.x, t = threadIdx.x;
    if (b < RA) {
        const float* p = psumA + (size_t)b * 32 * 512;
        float s0 = 0.f, s1 = 0.f;
#pragma unroll 8
        for (int r = 0; r < 32; ++r) { s0 += p[r * 512 + t]; s1 += p[r * 512 + 256 + t]; }
        psumA2[(size_t)b * 512 + t] = s0;
        psumA2[(size_t)b * 512 + 256 + t] = s1;
    } else {
        const int bi = b - RA;
        const float* p = psumB + (size_t)bi * 32 * 256;
        float s = 0.f;
#pragma unroll 8
        for (int r = 0; r < 32; ++r) s += p[r * 256 + t];
        psumB2[(size_t)bi * 256 + t] = s;
    }
}

// Final reduce -> s_j; c_j = scale_j * K_{j%2} @ s_j with K staged in LDS.
__global__ void k_cvec2(const float* __restrict__ rel,
                        const float* __restrict__ psumA2, const float* __restrict__ psumB2,
                        float* __restrict__ cvec) {
    const int j = blockIdx.x;        // 0..5: pos0,pos1,nh0,nh1,nt0,nt1
    const int tid = threadIdx.x;     // 256
    __shared__ float Kds[D * 129];
    __shared__ float red[256];
    __shared__ float sv[D];
    const float* Kp = rel + (size_t)(j & 1) * D * D;

    // stage K into LDS (padded stride 129 -> conflict-free matvec reads)
    for (int e = tid; e < D * D / 4; e += 256) {
        const int row = e >> 5, col = (e & 31) * 4;
        const float4 v = *reinterpret_cast<const float4*>(Kp + (size_t)row * D + col);
        float* dst = Kds + row * 129 + col;
        dst[0] = v.x; dst[1] = v.y; dst[2] = v.z; dst[3] = v.w;
    }

    const int g = tid >> 7, i = tid & 127;
    float s = 0.f;
    if (j == 1 || j == 5) {
        const int plane = (j == 1) ? 0 : 1;
        for (int b = g; b < RB; b += 2) s += psumB2[(size_t)b * 256 + plane * D + i];
    } else {
        const int plane = (j == 0) ? 0 : (j - 1);
        for (int b = g; b < RA; b += 2) s += psumA2[(size_t)b * 512 + plane * D + i];
    }
    red[tid] = s;
    __syncthreads();
    if (tid < 128) sv[i] = red[i] + red[128 + i];
    __syncthreads();

    if (tid < 128) {
        const float scale = (j == 2 || j == 3) ? (float)S_NEG : 1.0f;
        float acc = 0.f;
#pragma unroll
        for (int k = 0; k < D; k += 4)
            acc += Kds[i * 129 + k] * sv[k] + Kds[i * 129 + k + 1] * sv[k + 1]
                 + Kds[i * 129 + k + 2] * sv[k + 2] + Kds[i * 129 + k + 3] * sv[k + 3];
        cvec[j * D + i] = acc * scale;
    }
}

// PA[n*5+k] = emb_A[n].c_k;  PB[n] = emb_B[n].c_5.  Hoisted c-frags, 4-row unroll.
__global__ void k_scan2(const float* __restrict__ embA, const float* __restrict__ embB,
                        const float* __restrict__ cvec, float* __restrict__ PA,
                        float* __restrict__ PB) {
    __shared__ float sc[5 * D];
    const int tid = threadIdx.x;
    const int l = tid & 31;
    const int grp = tid >> 5;

    if ((int)blockIdx.x < GA) {
        for (int j = tid; j < 5 * D; j += 256) sc[j] = cvec[j];  // c0..c4
        __syncthreads();
        float4 cf[5];
#pragma unroll
        for (int p = 0; p < 5; ++p)
            cf[p] = *reinterpret_cast<const float4*>(sc + p * D + 4 * l);
        const int gid = blockIdx.x * 8 + grp;
        int r = gid * RPG;
        const int end = min(r + RPG, N_A);
        const float* base = embA + 4 * l;
        for (; r + 4 <= end; r += 4) {
            float4 x[4];
#pragma unroll
            for (int u = 0; u < 4; ++u)
                x[u] = *reinterpret_cast<const float4*>(base + (size_t)(r + u) * D);
            float p_[4][5];
#pragma unroll
            for (int u = 0; u < 4; ++u)
#pragma unroll
                for (int p = 0; p < 5; ++p) p_[u][p] = dot4(x[u], cf[p]);
#pragma unroll
            for (int u = 0; u < 4; ++u)
#pragma unroll
                for (int p = 0; p < 5; ++p) RED32(p_[u][p]);
            if (l < 4) {
                float* o = PA + (size_t)(r + l) * 5;
#pragma unroll
                for (int p = 0; p < 5; ++p)
                    o[p] = (l == 1) ? p_[1][p] : (l == 2) ? p_[2][p] : (l == 3) ? p_[3][p] : p_[0][p];
            }
        }
        for (; r < end; ++r) {
            const float4 x0 = *reinterpret_cast<const float4*>(base + (size_t)r * D);
            float q[5];
#pragma unroll
            for (int p = 0; p < 5; ++p) { q[p] = dot4(x0, cf[p]); RED32(q[p]); }
            if (l == 0) {
                float* o = PA + (size_t)r * 5;
#pragma unroll
                for (int p = 0; p < 5; ++p) o[p] = q[p];
            }
        }
    } else {
        for (int j = tid; j < D; j += 256) sc[j] = cvec[5 * D + j];  // c5
        __syncthreads();
        const float4 cf = *reinterpret_cast<const float4*>(sc + 4 * l);
        const int gid = (blockIdx.x - GA) * 8 + grp;
        int r = gid * RPG;
        const int end = min(r + RPG, N_B);
        const float* base = embB + 4 * l;
        for (; r + 4 <= end; r += 4) {
            float4 x[4];
#pragma unroll
            for (int u = 0; u < 4; ++u)
                x[u] = *reinterpret_cast<const float4*>(base + (size_t)(r + u) * D);
            float p_[4];
#pragma unroll
            for (int u = 0; u < 4; ++u) { p_[u] = dot4(x[u], cf); RED32(p_[u]); }
            if (l < 4)
                PB[r + l] = (l == 1) ? p_[1] : (l == 2) ? p_[2] : (l == 3) ? p_[3] : p_[0];
        }
        for (; r < end; ++r) {
            const float4 x0 = *reinterpret_cast<const float4*>(base + (size_t)r * D);
            float q = dot4(x0, cf); RED32(q);
            if (l == 0) PB[r] = q;
        }
    }
}

// Vectorized scatter: int4 index loads, float4 stores (segment bounds % 4 == 0).
__global__ void k_scatter(const int* __restrict__ ei0, const int* __restrict__ ei1,
                          const int* __restrict__ nh0, const int* __restrict__ nh1,
                          const int* __restrict__ nt0, const int* __restrict__ nt1,
                          const float* __restrict__ PA, const float* __restrict__ PB,
                          float* __restrict__ out) {
    const int total4 = (2 * E_EDGES + 4 * ES) / 4;  // 825000
    for (int t = blockIdx.x * blockDim.x + threadIdx.x; t < total4;
         t += gridDim.x * blockDim.x) {
        const int e = t * 4;
        float4 v;
        if (e < E_EDGES) {
            const int4 i4 = *reinterpret_cast<const int4*>(ei0 + e);
            v = make_float4(PA[(size_t)i4.x * 5], PA[(size_t)i4.y * 5],
                            PA[(size_t)i4.z * 5], PA[(size_t)i4.w * 5]);
        } else if (e < 2 * E_EDGES) {
            const int4 i4 = *reinterpret_cast<const int4*>(ei1 + (e - E_EDGES));
            v = make_float4(PA[(size_t)i4.x * 5 + 1], PA[(size_t)i4.y * 5 + 1],
                            PA[(size_t)i4.z * 5 + 1], PA[(size_t)i4.w * 5 + 1]);
        } else if (e < 2 * E_EDGES + ES) {
            const int4 i4 = *reinterpret_cast<const int4*>(nh0 + (e - 2 * E_EDGES));
            v = make_float4(PA[(size_t)i4.x * 5 + 2], PA[(size_t)i4.y * 5 + 2],
                            PA[(size_t)i4.z * 5 + 2], PA[(size_t)i4.w * 5 + 2]);
        } else if (e < 2 * E_EDGES + 2 * ES) {
            const int4 i4 = *reinterpret_cast<const int4*>(nh1 + (e - 2 * E_EDGES - ES));
            v = make_float4(PA[(size_t)i4.x * 5 + 3], PA[(size_t)i4.y * 5 + 3],
                            PA[(size_t)i4.z * 5 + 3], PA[(size_t)i4.w * 5 + 3]);
        } else if (e < 2 * E_EDGES + 3 * ES) {
            const int i = e - 2 * E_EDGES - 2 * ES;
            const float s = PA[(size_t)nt0[(i >> 4) << 4] * 5 + 4];
            v = make_float4(s, s, s, s);
        } else {
            const int i = e - 2 * E_EDGES - 3 * ES;
            const float s = PB[nt1[(i >> 4) << 4]];
            v = make_float4(s, s, s, s);
        }
        *reinterpret_cast<float4*>(out + e) = v;
    }
}

extern "C" void kernel_launch(void* const* d_in, const int* in_sizes, int n_in,
                              void* d_out, int out_size, void* d_ws, size_t ws_size,
                              hipStream_t stream) {
    const float* embA = (const float*)d_in[0];
    const float* embB = (const float*)d_in[1];
    const float* rel  = (const float*)d_in[2];
    const int* ei0 = (const int*)d_in[3];
    const int* ei1 = (const int*)d_in[4];
    const int* nh0 = (const int*)d_in[5];
    const int* nh1 = (const int*)d_in[6];
    const int* nt0 = (const int*)d_in[7];
    const int* nt1 = (const int*)d_in[8];
    float* out = (float*)d_out;

    uint32_t* partA = (uint32_t*)d_ws;                        // 152*CHUNK
    uint32_t* partB = partA + (size_t)152 * CHUNK;            // 68*CHUNK
    float4* cwA = (float4*)(partB + (size_t)B_SLABS * CHUNK); // N_A float4
    float2* cwB = (float2*)(cwA + N_A);                       // N_B float2
    float* psumA = (float*)(cwB + N_B);                       // GA*512
    float* psumB = psumA + (size_t)GA * 512;                  // GB*256
    float* psumA2 = psumB + (size_t)GB * 256;                 // RA*512
    float* psumB2 = psumA2 + (size_t)RA * 512;                // RB*256
    float* cvec  = psumB2 + (size_t)RB * 256;                 // 6*D
    float* PA    = cvec + 6 * D;                              // N_A*5
    float* PB    = PA + (size_t)N_A * 5;                      // N_B

    k_hist<<<220, 256, 0, stream>>>(ei0, ei1, nh0, nh1, nt0, nt1, partA, partB);
    k_reduceC<<<(N_A + N_B + 255) / 256, 256, 0, stream>>>(partA, partB, cwA, cwB);
    k_scan1<<<GA + GB, 256, 0, stream>>>(embA, embB, cwA, cwB, psumA, psumB);
    k_red1<<<RA + RB, 256, 0, stream>>>(psumA, psumB, psumA2, psumB2);
    k_cvec2<<<6, 256, 0, stream>>>(rel, psumA2, psumB2, cvec);
    k_scan2<<<GA + GB, 256, 0, stream>>>(embA, embB, cvec, PA, PB);
    k_scatter<<<2048, 256, 0, stream>>>(ei0, ei1, nh0, nh1, nt0, nt1, PA, PB, out);
}